// Round 9
// baseline (442.133 us; speedup 1.0000x reference)
//
#include <hip/hip_runtime.h>

static constexpr int FDIM = 128;
static constexpr int ND1  = 131072;
static constexpr int ND2  = 8192;
static constexpr int PADW = 64;   // padded adjacency slots/row; P(deg>=64)~1e-23 for Poisson(15)
static constexpr int LDP  = 56;   // ushort stride for A/W staging tiles
static constexpr int AML  = 136;  // ushort stride for mean tile (272B rows, 16B-aligned)

using bf16x8 = __attribute__((ext_vector_type(8))) short;
using u16x8  = __attribute__((ext_vector_type(8))) unsigned short;
using f32x4  = __attribute__((ext_vector_type(4))) float;

static __device__ __forceinline__ unsigned short f2bf(float f) {
  unsigned u = __float_as_uint(f);
  u = (u + 0x7FFFu + ((u >> 16) & 1u)) >> 16;   // round-to-nearest-even
  return (unsigned short)u;
}
static __device__ __forceinline__ float bf2f(unsigned short s) {
  return __uint_as_float(((unsigned)s) << 16);
}

// ---- single-pass padded-adjacency build (both graphs) + weight prep ---------
__global__ void build_pad(const int* __restrict__ e1s, const int* __restrict__ e1d,
                          const int* __restrict__ e2s, const int* __restrict__ e2d,
                          int* __restrict__ cnt1, int* __restrict__ cnt2,
                          int* __restrict__ pad1, int* __restrict__ pad2,
                          int E1, int E2, int nb_fill,
                          const float* __restrict__ Ws1, const float* __restrict__ Wn1,
                          unsigned short* __restrict__ Wt1,
                          const float* __restrict__ Ws2, const float* __restrict__ Wn2,
                          unsigned short* __restrict__ Wt2) {
  if ((int)blockIdx.x >= nb_fill) {   // ---- weight prep: 256 trailing blocks ----
    int t = (blockIdx.x - nb_fill) * 256 + threadIdx.x;   // 0..65535
    int which = t >> 15;
    int r = t & 32767;
    int col = r >> 8, k = r & 255;
    const float* Ws = which ? Ws2 : Ws1;
    const float* Wn = which ? Wn2 : Wn1;
    unsigned short* Wt = which ? Wt2 : Wt1;
    float v = (k < 128) ? Ws[k * 128 + col] : Wn[(k - 128) * 128 + col];
    Wt[col * 256 + k] = f2bf(v);
    return;
  }
  const int n1 = E1 >> 2, n2 = E2 >> 2;
  int t = blockIdx.x * 256 + threadIdx.x;
  if (t < n1) {
    int4 d = ((const int4*)e1d)[t];
    int4 s = ((const int4*)e1s)[t];
    int p;
    p = atomicAdd(&cnt1[d.x], 1); if (p < PADW) pad1[d.x * PADW + p] = s.x;
    p = atomicAdd(&cnt1[d.y], 1); if (p < PADW) pad1[d.y * PADW + p] = s.y;
    p = atomicAdd(&cnt1[d.z], 1); if (p < PADW) pad1[d.z * PADW + p] = s.z;
    p = atomicAdd(&cnt1[d.w], 1); if (p < PADW) pad1[d.w * PADW + p] = s.w;
  } else if (t < n1 + n2) {
    int4 d = ((const int4*)e2d)[t - n1];
    int4 s = ((const int4*)e2s)[t - n1];
    int p;
    p = atomicAdd(&cnt2[d.x], 1); if (p < PADW) pad2[d.x * PADW + p] = s.x;
    p = atomicAdd(&cnt2[d.y], 1); if (p < PADW) pad2[d.y * PADW + p] = s.y;
    p = atomicAdd(&cnt2[d.z], 1); if (p < PADW) pad2[d.z * PADW + p] = s.z;
    p = atomicAdd(&cnt2[d.w], 1); if (p < PADW) pad2[d.w * PADW + p] = s.w;
  }
  if (blockIdx.x == 0) {               // generic tails (E%4)
    int tt = threadIdx.x;
    if (tt < (E1 & 3)) {
      int e = E1 - 1 - tt, d = e1d[e];
      int p = atomicAdd(&cnt1[d], 1); if (p < PADW) pad1[d * PADW + p] = e1s[e];
    }
    int t2 = tt - 8;
    if (t2 >= 0 && t2 < (E2 & 3)) {
      int e = E2 - 1 - t2, d = e2d[e];
      int p = atomicAdd(&cnt2[d], 1); if (p < PADW) pad2[d * PADW + p] = e2s[e];
    }
  }
}

// ---- fused layer: phase 0 gather-mean (rows row0..+127 -> LDS bf16 tile),
//      phase 1 MFMA GEMM Out = act([Self | Mean] @ [Wself;Wneigh] + b).
// L1: self/src table f32 (x), relu, bf16 out.  !L1: bf16 (h), no relu, f32 out.
template<bool L1>
__global__ __launch_bounds__(256)
void fused_layer(const void* __restrict__ selfp,
                 const int* __restrict__ pad, const int* __restrict__ cnt,
                 const unsigned short* __restrict__ Wt,
                 const float* __restrict__ bias,
                 void* __restrict__ Outp)
{
  __shared__ unsigned short AmL[128 * AML];   // mean rows, bf16  (34 KB)
  __shared__ unsigned short Asb[128 * LDP];   // A staging        (14.3 KB)
  __shared__ unsigned short Wsb[128 * LDP];   // W staging        (14.3 KB)
  const int tid  = threadIdx.x;
  const int lane = tid & 63;
  const int w    = tid >> 6;
  const int half = lane >> 5;
  const int sub  = lane & 31;
  const int row0 = blockIdx.x * 128;

  // ---- phase 0: gather-mean, proven v3 shape (half-wave per row, 2 rows/wave,
  //      8-deep unconditional clamped loads + fmaf masks) ----
  for (int i = 0; i < 16; ++i) {
    const int rl   = w * 32 + i * 2 + half;
    const int row  = row0 + rl;
    const int degt = cnt[row];
    const int deg  = degt < PADW ? degt : PADW;   // index-safety clamp
    float ax = 0.f, ay = 0.f, az = 0.f, aw = 0.f;
    for (int base = 0; base < deg; base += 32) {
      int t = base + sub;
      int idx = pad[(size_t)row * PADW + (t < deg ? t : deg - 1)];  // coalesced, clamped
      const int lim = (deg - base) < 32 ? (deg - base) : 32;
      for (int b = 0; b < lim; b += 8) {
        if (L1) {
          float4 v[8];
          #pragma unroll
          for (int j = 0; j < 8; ++j) {
            int e = __shfl(idx, half * 32 + b + j);
            v[j] = *(const float4*)((const float*)selfp + (size_t)e * FDIM + sub * 4);
          }
          #pragma unroll
          for (int j = 0; j < 8; ++j) {
            float mk = (b + j) < lim ? 1.f : 0.f;
            ax = fmaf(v[j].x, mk, ax); ay = fmaf(v[j].y, mk, ay);
            az = fmaf(v[j].z, mk, az); aw = fmaf(v[j].w, mk, aw);
          }
        } else {
          ushort4 v[8];
          #pragma unroll
          for (int j = 0; j < 8; ++j) {
            int e = __shfl(idx, half * 32 + b + j);
            v[j] = *(const ushort4*)((const unsigned short*)selfp + (size_t)e * FDIM + sub * 4);
          }
          #pragma unroll
          for (int j = 0; j < 8; ++j) {
            float mk = (b + j) < lim ? 1.f : 0.f;
            ax = fmaf(bf2f(v[j].x), mk, ax); ay = fmaf(bf2f(v[j].y), mk, ay);
            az = fmaf(bf2f(v[j].z), mk, az); aw = fmaf(bf2f(v[j].w), mk, aw);
          }
        }
      }
    }
    const float inv = 1.f / (float)(degt > 1 ? degt : 1);
    ushort4 o;
    o.x = f2bf(ax * inv); o.y = f2bf(ay * inv);
    o.z = f2bf(az * inv); o.w = f2bf(aw * inv);
    *(ushort4*)&AmL[rl * AML + sub * 4] = o;
  }
  __syncthreads();

  // ---- phase 1: MFMA GEMM (K=256: chunks 0-3 self from global, 4-7 mean from AmL) ----
  const int p = lane & 15;
  const int q = lane >> 4;
  f32x4 acc[2][8];
  #pragma unroll
  for (int m = 0; m < 2; ++m)
    #pragma unroll
    for (int n = 0; n < 8; ++n) acc[m][n] = (f32x4){0.f, 0.f, 0.f, 0.f};

  const int sr = tid >> 1;            // staging row/col 0..127
  const int sk = (tid & 1) * 16;      // staging k-half

  for (int c = 0; c < 8; ++c) {
    const int kc = c * 32;
    const int kl = kc & 127;
    {   // stage W chunk (bf16, [col][k] layout)
      const unsigned short* wsrc = Wt + (size_t)sr * 256 + kc + sk;
      u16x8 a = *(const u16x8*)(wsrc);
      u16x8 b = *(const u16x8*)(wsrc + 8);
      *(u16x8*)&Wsb[sr * LDP + sk]     = a;
      *(u16x8*)&Wsb[sr * LDP + sk + 8] = b;
    }
    if (c >= 4) {       // mean chunk: LDS -> LDS via regs
      u16x8 a = *(const u16x8*)&AmL[sr * AML + kl + sk];
      u16x8 b = *(const u16x8*)&AmL[sr * AML + kl + sk + 8];
      *(u16x8*)&Asb[sr * LDP + sk]     = a;
      *(u16x8*)&Asb[sr * LDP + sk + 8] = b;
    } else if (!L1) {   // self chunk, bf16 source
      const unsigned short* asrc =
          (const unsigned short*)selfp + (size_t)(row0 + sr) * FDIM + kl + sk;
      u16x8 a = *(const u16x8*)(asrc);
      u16x8 b = *(const u16x8*)(asrc + 8);
      *(u16x8*)&Asb[sr * LDP + sk]     = a;
      *(u16x8*)&Asb[sr * LDP + sk + 8] = b;
    } else {            // self chunk, f32 source -> bf16
      const float* asrc = (const float*)selfp + (size_t)(row0 + sr) * FDIM + kl + sk;
      float4 f0 = *(const float4*)(asrc);
      float4 f1 = *(const float4*)(asrc + 4);
      float4 f2 = *(const float4*)(asrc + 8);
      float4 f3 = *(const float4*)(asrc + 12);
      u16x8 a, b;
      a[0] = f2bf(f0.x); a[1] = f2bf(f0.y); a[2] = f2bf(f0.z); a[3] = f2bf(f0.w);
      a[4] = f2bf(f1.x); a[5] = f2bf(f1.y); a[6] = f2bf(f1.z); a[7] = f2bf(f1.w);
      b[0] = f2bf(f2.x); b[1] = f2bf(f2.y); b[2] = f2bf(f2.z); b[3] = f2bf(f2.w);
      b[4] = f2bf(f3.x); b[5] = f2bf(f3.y); b[6] = f2bf(f3.z); b[7] = f2bf(f3.w);
      *(u16x8*)&Asb[sr * LDP + sk]     = a;
      *(u16x8*)&Asb[sr * LDP + sk + 8] = b;
    }
    __syncthreads();
    bf16x8 af[2];
    #pragma unroll
    for (int m = 0; m < 2; ++m)
      af[m] = *(const bf16x8*)&Asb[(w * 32 + m * 16 + p) * LDP + q * 8];
    #pragma unroll
    for (int n = 0; n < 8; ++n) {
      bf16x8 bfr = *(const bf16x8*)&Wsb[(n * 16 + p) * LDP + q * 8];
      acc[0][n] = __builtin_amdgcn_mfma_f32_16x16x32_bf16(af[0], bfr, acc[0][n], 0, 0, 0);
      acc[1][n] = __builtin_amdgcn_mfma_f32_16x16x32_bf16(af[1], bfr, acc[1][n], 0, 0, 0);
    }
    __syncthreads();
  }

  #pragma unroll
  for (int n = 0; n < 8; ++n) {
    const int col = n * 16 + p;
    const float bv = bias[col];
    #pragma unroll
    for (int m = 0; m < 2; ++m) {
      #pragma unroll
      for (int r = 0; r < 4; ++r) {
        float y = acc[m][n][r] + bv;
        if (L1) y = fmaxf(y, 0.f);
        const size_t grow = (size_t)(row0 + w * 32 + m * 16 + q * 4 + r);
        if (L1) ((unsigned short*)Outp)[grow * FDIM + col] = f2bf(y);
        else    ((float*)Outp)[grow * FDIM + col] = y;
      }
    }
  }
}

extern "C" void kernel_launch(void* const* d_in, const int* in_sizes, int n_in,
                              void* d_out, int out_size, void* d_ws, size_t ws_size,
                              hipStream_t stream) {
  const float* x   = (const float*)d_in[0];
  const int*   e1s = (const int*)d_in[1];
  const int*   e1d = (const int*)d_in[2];
  const int*   e2s = (const int*)d_in[3];
  const int*   e2d = (const int*)d_in[4];
  const float* Ws1 = (const float*)d_in[7];
  const float* Wn1 = (const float*)d_in[8];
  const float* b1  = (const float*)d_in[9];
  const float* Ws2 = (const float*)d_in[10];
  const float* Wn2 = (const float*)d_in[11];
  const float* b2  = (const float*)d_in[12];
  const int E1 = in_sizes[1];
  const int E2 = in_sizes[3];

  char* pw = (char*)d_ws;
  unsigned short* h   = (unsigned short*)pw; pw += (size_t)ND1 * FDIM * 2;   // 32 MB
  unsigned short* Wt1 = (unsigned short*)pw; pw += (size_t)FDIM * 256 * 2;   // 64 KB
  unsigned short* Wt2 = (unsigned short*)pw; pw += (size_t)FDIM * 256 * 2;
  int* pad1 = (int*)pw; pw += (size_t)ND1 * PADW * 4;                         // 33.5 MB
  int* pad2 = (int*)pw; pw += (size_t)ND2 * PADW * 4;                         //  2 MB
  int* cnt1 = (int*)pw; pw += (size_t)ND1 * 4;                                // 512 KB
  int* cnt2 = (int*)pw; pw += (size_t)ND2 * 4;                                //  32 KB

  hipMemsetAsync(cnt1, 0, (size_t)(ND1 + ND2) * 4, stream);

  const int n4 = (E1 >> 2) + (E2 >> 2);
  const int nb_fill = (n4 + 255) / 256;
  build_pad<<<nb_fill + 256, 256, 0, stream>>>(e1s, e1d, e2s, e2d, cnt1, cnt2,
                                               pad1, pad2, E1, E2, nb_fill,
                                               Ws1, Wn1, Wt1, Ws2, Wn2, Wt2);

  // Layer 1: fused gather+GEMM+ReLU -> h (bf16)
  fused_layer<true ><<<ND1 / 128, 256, 0, stream>>>(x, pad1, cnt1, Wt1, b1, h);
  // Layer 2: fused gather+GEMM -> out (f32)
  fused_layer<false><<<ND2 / 128, 256, 0, stream>>>(h, pad2, cnt2, Wt2, b2, (float*)d_out);
}

// Round 10
// 439.404 us; speedup vs baseline: 1.0062x; 1.0062x over previous
//
#include <hip/hip_runtime.h>

static constexpr int FDIM = 128;
static constexpr int ND1  = 131072;
static constexpr int ND2  = 8192;
static constexpr int PADW = 64;   // padded adjacency slots/row; P(deg>=64)~1e-23 for Poisson(15)
static constexpr int LDP  = 56;   // ushort stride for A/W staging tiles
static constexpr int AML  = 136;  // ushort stride for fused mean tile

using bf16x8 = __attribute__((ext_vector_type(8))) short;
using u16x8  = __attribute__((ext_vector_type(8))) unsigned short;
using f32x4  = __attribute__((ext_vector_type(4))) float;

static __device__ __forceinline__ unsigned short f2bf(float f) {
  unsigned u = __float_as_uint(f);
  u = (u + 0x7FFFu + ((u >> 16) & 1u)) >> 16;   // round-to-nearest-even
  return (unsigned short)u;
}
static __device__ __forceinline__ float bf2f(unsigned short s) {
  return __uint_as_float(((unsigned)s) << 16);
}

// ---- build: graph-1 padded adjacency + weight prep (Wt1, Wt2) ---------------
__global__ void build1(const int* __restrict__ e1s, const int* __restrict__ e1d,
                       int* __restrict__ cnt1, int* __restrict__ pad1,
                       int E1, int nb_fill,
                       const float* __restrict__ Ws1, const float* __restrict__ Wn1,
                       unsigned short* __restrict__ Wt1,
                       const float* __restrict__ Ws2, const float* __restrict__ Wn2,
                       unsigned short* __restrict__ Wt2) {
  if ((int)blockIdx.x >= nb_fill) {   // ---- weight prep: 256 trailing blocks ----
    int t = (blockIdx.x - nb_fill) * 256 + threadIdx.x;   // 0..65535
    int which = t >> 15;
    int r = t & 32767;
    int col = r >> 8, k = r & 255;
    const float* Ws = which ? Ws2 : Ws1;
    const float* Wn = which ? Wn2 : Wn1;
    unsigned short* Wt = which ? Wt2 : Wt1;
    float v = (k < 128) ? Ws[k * 128 + col] : Wn[(k - 128) * 128 + col];
    Wt[col * 256 + k] = f2bf(v);
    return;
  }
  const int n1 = E1 >> 2;
  int t = blockIdx.x * 256 + threadIdx.x;
  if (t < n1) {
    int4 d = ((const int4*)e1d)[t];
    int4 s = ((const int4*)e1s)[t];
    int p;
    p = atomicAdd(&cnt1[d.x], 1); if (p < PADW) pad1[d.x * PADW + p] = s.x;
    p = atomicAdd(&cnt1[d.y], 1); if (p < PADW) pad1[d.y * PADW + p] = s.y;
    p = atomicAdd(&cnt1[d.z], 1); if (p < PADW) pad1[d.z * PADW + p] = s.z;
    p = atomicAdd(&cnt1[d.w], 1); if (p < PADW) pad1[d.w * PADW + p] = s.w;
  }
  if (blockIdx.x == 0) {               // generic tail (E1 % 4)
    int tt = threadIdx.x;
    if (tt < (E1 & 3)) {
      int e = E1 - 1 - tt, d = e1d[e];
      int p = atomicAdd(&cnt1[d], 1); if (p < PADW) pad1[d * PADW + p] = e1s[e];
    }
  }
}

// ---- gather-mean layer 1 (R8 proven shape) + graph-2 build in trailing blocks
__global__ __launch_bounds__(256)
void gather_mean1(const float* __restrict__ src, const int* __restrict__ pad,
                  const int* __restrict__ cnt, unsigned short* __restrict__ out,
                  int nrows, int nb_gather,
                  const int* __restrict__ e2s, const int* __restrict__ e2d,
                  int* __restrict__ cnt2, int* __restrict__ pad2, int E2) {
  if ((int)blockIdx.x >= nb_gather) {   // ---- graph-2 build, hidden under gather ----
    const int n2 = E2 >> 2;
    int t = (blockIdx.x - nb_gather) * 256 + threadIdx.x;
    if (t < n2) {
      int4 d = ((const int4*)e2d)[t];
      int4 s = ((const int4*)e2s)[t];
      int p;
      p = atomicAdd(&cnt2[d.x], 1); if (p < PADW) pad2[d.x * PADW + p] = s.x;
      p = atomicAdd(&cnt2[d.y], 1); if (p < PADW) pad2[d.y * PADW + p] = s.y;
      p = atomicAdd(&cnt2[d.z], 1); if (p < PADW) pad2[d.z * PADW + p] = s.z;
      p = atomicAdd(&cnt2[d.w], 1); if (p < PADW) pad2[d.w * PADW + p] = s.w;
    }
    if (blockIdx.x == (unsigned)nb_gather) {   // tail (E2 % 4)
      int tt = threadIdx.x;
      if (tt < (E2 & 3)) {
        int e = E2 - 1 - tt, d = e2d[e];
        int p = atomicAdd(&cnt2[d], 1); if (p < PADW) pad2[d * PADW + p] = e2s[e];
      }
    }
    return;
  }
  const int lane = threadIdx.x & 63;
  const int half = lane >> 5;
  const int sub  = lane & 31;
  const int wid  = (int)((blockIdx.x * 256u + threadIdx.x) >> 6);
  const int row  = wid * 2 + half;
  if (row >= nrows) return;
  const int degt = cnt[row];
  const int deg  = degt < PADW ? degt : PADW;
  float ax = 0.f, ay = 0.f, az = 0.f, aw = 0.f;
  for (int base = 0; base < deg; base += 32) {
    int t = base + sub;
    int idx = pad[(size_t)row * PADW + (t < deg ? t : deg - 1)];   // coalesced, clamped
    const int lim = (deg - base) < 32 ? (deg - base) : 32;
    for (int b = 0; b < lim; b += 8) {
      float4 v[8];
      #pragma unroll
      for (int j = 0; j < 8; ++j) {
        int e = __shfl(idx, half * 32 + b + j);
        v[j] = *(const float4*)(src + (size_t)e * FDIM + sub * 4);
      }
      #pragma unroll
      for (int j = 0; j < 8; ++j) {
        float mk = (b + j) < lim ? 1.f : 0.f;
        ax = fmaf(v[j].x, mk, ax); ay = fmaf(v[j].y, mk, ay);
        az = fmaf(v[j].z, mk, az); aw = fmaf(v[j].w, mk, aw);
      }
    }
  }
  const float inv = 1.f / (float)(degt > 1 ? degt : 1);
  ushort4 o;
  o.x = f2bf(ax * inv); o.y = f2bf(ay * inv);
  o.z = f2bf(az * inv); o.w = f2bf(aw * inv);
  *(ushort4*)(out + (size_t)row * FDIM + sub * 4) = o;
}

// ---- MFMA GEMM layer 1: h = relu([x | agg1] @ [Ws1;Wn1] + b1), bf16 out -----
__global__ __launch_bounds__(256)
void gemm_mfma1(const float* __restrict__ Ax,
                const unsigned short* __restrict__ Am,
                const unsigned short* __restrict__ Wt,
                const float* __restrict__ bias,
                unsigned short* __restrict__ Out) {
  __shared__ unsigned short Asb[128 * LDP];
  __shared__ unsigned short Wsb[128 * LDP];
  const int tid  = threadIdx.x;
  const int lane = tid & 63;
  const int w    = tid >> 6;
  const int row0 = blockIdx.x * 128;
  const int p    = lane & 15;
  const int q    = lane >> 4;

  f32x4 acc[2][8];
  #pragma unroll
  for (int m = 0; m < 2; ++m)
    #pragma unroll
    for (int n = 0; n < 8; ++n) acc[m][n] = (f32x4){0.f, 0.f, 0.f, 0.f};

  const int sr = tid >> 1;
  const int sk = (tid & 1) * 16;

  for (int c = 0; c < 8; ++c) {
    const int kc = c * 32;
    const int kl = kc & 127;
    {
      const unsigned short* wsrc = Wt + (size_t)sr * 256 + kc + sk;
      u16x8 a = *(const u16x8*)(wsrc);
      u16x8 b = *(const u16x8*)(wsrc + 8);
      *(u16x8*)&Wsb[sr * LDP + sk]     = a;
      *(u16x8*)&Wsb[sr * LDP + sk + 8] = b;
    }
    if (c >= 4) {
      const unsigned short* asrc = Am + (size_t)(row0 + sr) * FDIM + kl + sk;
      u16x8 a = *(const u16x8*)(asrc);
      u16x8 b = *(const u16x8*)(asrc + 8);
      *(u16x8*)&Asb[sr * LDP + sk]     = a;
      *(u16x8*)&Asb[sr * LDP + sk + 8] = b;
    } else {
      const float* asrc = Ax + (size_t)(row0 + sr) * FDIM + kl + sk;
      float4 f0 = *(const float4*)(asrc);
      float4 f1 = *(const float4*)(asrc + 4);
      float4 f2 = *(const float4*)(asrc + 8);
      float4 f3 = *(const float4*)(asrc + 12);
      u16x8 a, b;
      a[0] = f2bf(f0.x); a[1] = f2bf(f0.y); a[2] = f2bf(f0.z); a[3] = f2bf(f0.w);
      a[4] = f2bf(f1.x); a[5] = f2bf(f1.y); a[6] = f2bf(f1.z); a[7] = f2bf(f1.w);
      b[0] = f2bf(f2.x); b[1] = f2bf(f2.y); b[2] = f2bf(f2.z); b[3] = f2bf(f2.w);
      b[4] = f2bf(f3.x); b[5] = f2bf(f3.y); b[6] = f2bf(f3.z); b[7] = f2bf(f3.w);
      *(u16x8*)&Asb[sr * LDP + sk]     = a;
      *(u16x8*)&Asb[sr * LDP + sk + 8] = b;
    }
    __syncthreads();
    bf16x8 af[2];
    #pragma unroll
    for (int m = 0; m < 2; ++m)
      af[m] = *(const bf16x8*)&Asb[(w * 32 + m * 16 + p) * LDP + q * 8];
    #pragma unroll
    for (int n = 0; n < 8; ++n) {
      bf16x8 bfr = *(const bf16x8*)&Wsb[(n * 16 + p) * LDP + q * 8];
      acc[0][n] = __builtin_amdgcn_mfma_f32_16x16x32_bf16(af[0], bfr, acc[0][n], 0, 0, 0);
      acc[1][n] = __builtin_amdgcn_mfma_f32_16x16x32_bf16(af[1], bfr, acc[1][n], 0, 0, 0);
    }
    __syncthreads();
  }

  #pragma unroll
  for (int n = 0; n < 8; ++n) {
    const int col = n * 16 + p;
    const float bv = bias[col];
    #pragma unroll
    for (int m = 0; m < 2; ++m) {
      #pragma unroll
      for (int r = 0; r < 4; ++r) {
        float y = fmaxf(acc[m][n][r] + bv, 0.f);
        const size_t grow = (size_t)(row0 + w * 32 + m * 16 + q * 4 + r);
        Out[grow * FDIM + col] = f2bf(y);
      }
    }
  }
}

// ---- fused layer 2: gather-mean(h) -> LDS, then GEMM -> f32 out -------------
__global__ __launch_bounds__(256)
void fused_layer2(const unsigned short* __restrict__ selfp,
                  const int* __restrict__ pad, const int* __restrict__ cnt,
                  const unsigned short* __restrict__ Wt,
                  const float* __restrict__ bias,
                  float* __restrict__ Outp)
{
  __shared__ unsigned short AmL[128 * AML];
  __shared__ unsigned short Asb[128 * LDP];
  __shared__ unsigned short Wsb[128 * LDP];
  const int tid  = threadIdx.x;
  const int lane = tid & 63;
  const int w    = tid >> 6;
  const int half = lane >> 5;
  const int sub  = lane & 31;
  const int row0 = blockIdx.x * 128;

  for (int i = 0; i < 16; ++i) {
    const int rl   = w * 32 + i * 2 + half;
    const int row  = row0 + rl;
    const int degt = cnt[row];
    const int deg  = degt < PADW ? degt : PADW;
    float ax = 0.f, ay = 0.f, az = 0.f, aw = 0.f;
    for (int base = 0; base < deg; base += 32) {
      int t = base + sub;
      int idx = pad[(size_t)row * PADW + (t < deg ? t : deg - 1)];
      const int lim = (deg - base) < 32 ? (deg - base) : 32;
      for (int b = 0; b < lim; b += 8) {
        ushort4 v[8];
        #pragma unroll
        for (int j = 0; j < 8; ++j) {
          int e = __shfl(idx, half * 32 + b + j);
          v[j] = *(const ushort4*)(selfp + (size_t)e * FDIM + sub * 4);
        }
        #pragma unroll
        for (int j = 0; j < 8; ++j) {
          float mk = (b + j) < lim ? 1.f : 0.f;
          ax = fmaf(bf2f(v[j].x), mk, ax); ay = fmaf(bf2f(v[j].y), mk, ay);
          az = fmaf(bf2f(v[j].z), mk, az); aw = fmaf(bf2f(v[j].w), mk, aw);
        }
      }
    }
    const float inv = 1.f / (float)(degt > 1 ? degt : 1);
    ushort4 o;
    o.x = f2bf(ax * inv); o.y = f2bf(ay * inv);
    o.z = f2bf(az * inv); o.w = f2bf(aw * inv);
    *(ushort4*)&AmL[rl * AML + sub * 4] = o;
  }
  __syncthreads();

  const int p = lane & 15;
  const int q = lane >> 4;
  f32x4 acc[2][8];
  #pragma unroll
  for (int m = 0; m < 2; ++m)
    #pragma unroll
    for (int n = 0; n < 8; ++n) acc[m][n] = (f32x4){0.f, 0.f, 0.f, 0.f};

  const int sr = tid >> 1;
  const int sk = (tid & 1) * 16;

  for (int c = 0; c < 8; ++c) {
    const int kc = c * 32;
    const int kl = kc & 127;
    {
      const unsigned short* wsrc = Wt + (size_t)sr * 256 + kc + sk;
      u16x8 a = *(const u16x8*)(wsrc);
      u16x8 b = *(const u16x8*)(wsrc + 8);
      *(u16x8*)&Wsb[sr * LDP + sk]     = a;
      *(u16x8*)&Wsb[sr * LDP + sk + 8] = b;
    }
    if (c >= 4) {
      u16x8 a = *(const u16x8*)&AmL[sr * AML + kl + sk];
      u16x8 b = *(const u16x8*)&AmL[sr * AML + kl + sk + 8];
      *(u16x8*)&Asb[sr * LDP + sk]     = a;
      *(u16x8*)&Asb[sr * LDP + sk + 8] = b;
    } else {
      const unsigned short* asrc = selfp + (size_t)(row0 + sr) * FDIM + kl + sk;
      u16x8 a = *(const u16x8*)(asrc);
      u16x8 b = *(const u16x8*)(asrc + 8);
      *(u16x8*)&Asb[sr * LDP + sk]     = a;
      *(u16x8*)&Asb[sr * LDP + sk + 8] = b;
    }
    __syncthreads();
    bf16x8 af[2];
    #pragma unroll
    for (int m = 0; m < 2; ++m)
      af[m] = *(const bf16x8*)&Asb[(w * 32 + m * 16 + p) * LDP + q * 8];
    #pragma unroll
    for (int n = 0; n < 8; ++n) {
      bf16x8 bfr = *(const bf16x8*)&Wsb[(n * 16 + p) * LDP + q * 8];
      acc[0][n] = __builtin_amdgcn_mfma_f32_16x16x32_bf16(af[0], bfr, acc[0][n], 0, 0, 0);
      acc[1][n] = __builtin_amdgcn_mfma_f32_16x16x32_bf16(af[1], bfr, acc[1][n], 0, 0, 0);
    }
    __syncthreads();
  }

  #pragma unroll
  for (int n = 0; n < 8; ++n) {
    const int col = n * 16 + p;
    const float bv = bias[col];
    #pragma unroll
    for (int m = 0; m < 2; ++m) {
      #pragma unroll
      for (int r = 0; r < 4; ++r) {
        float y = acc[m][n][r] + bv;
        const size_t grow = (size_t)(row0 + w * 32 + m * 16 + q * 4 + r);
        Outp[grow * FDIM + col] = y;
      }
    }
  }
}

extern "C" void kernel_launch(void* const* d_in, const int* in_sizes, int n_in,
                              void* d_out, int out_size, void* d_ws, size_t ws_size,
                              hipStream_t stream) {
  const float* x   = (const float*)d_in[0];
  const int*   e1s = (const int*)d_in[1];
  const int*   e1d = (const int*)d_in[2];
  const int*   e2s = (const int*)d_in[3];
  const int*   e2d = (const int*)d_in[4];
  const float* Ws1 = (const float*)d_in[7];
  const float* Wn1 = (const float*)d_in[8];
  const float* b1  = (const float*)d_in[9];
  const float* Ws2 = (const float*)d_in[10];
  const float* Wn2 = (const float*)d_in[11];
  const float* b2  = (const float*)d_in[12];
  const int E1 = in_sizes[1];
  const int E2 = in_sizes[3];

  char* pw = (char*)d_ws;
  unsigned short* agg1 = (unsigned short*)pw; pw += (size_t)ND1 * FDIM * 2;   // 32 MB
  unsigned short* h    = (unsigned short*)pw; pw += (size_t)ND1 * FDIM * 2;   // 32 MB
  unsigned short* Wt1  = (unsigned short*)pw; pw += (size_t)FDIM * 256 * 2;   // 64 KB
  unsigned short* Wt2  = (unsigned short*)pw; pw += (size_t)FDIM * 256 * 2;
  int* pad1 = (int*)pw; pw += (size_t)ND1 * PADW * 4;                          // 33.5 MB
  int* pad2 = (int*)pw; pw += (size_t)ND2 * PADW * 4;                          //  2 MB
  int* cnt1 = (int*)pw; pw += (size_t)ND1 * 4;                                 // 512 KB
  int* cnt2 = (int*)pw; pw += (size_t)ND2 * 4;                                 //  32 KB

  hipMemsetAsync(cnt1, 0, (size_t)(ND1 + ND2) * 4, stream);

  // dispatch 2: graph-1 adjacency build + weight prep
  const int nb_fill1 = ((E1 >> 2) + 255) / 256;
  build1<<<nb_fill1 + 256, 256, 0, stream>>>(e1s, e1d, cnt1, pad1, E1, nb_fill1,
                                             Ws1, Wn1, Wt1, Ws2, Wn2, Wt2);

  // dispatch 3: layer-1 gather (BW-bound) with graph-2 build hidden in trailing blocks
  const int nb_gather = ND1 / 8;
  const int nb_fill2  = ((E2 >> 2) + 255) / 256;
  gather_mean1<<<nb_gather + nb_fill2, 256, 0, stream>>>(x, pad1, cnt1, agg1, ND1,
                                                         nb_gather, e2s, e2d,
                                                         cnt2, pad2, E2);

  // dispatch 4: layer-1 GEMM+ReLU -> h (bf16)
  gemm_mfma1<<<ND1 / 128, 256, 0, stream>>>(x, agg1, Wt1, b1, h);

  // dispatch 5: fused layer 2 -> out (f32)
  fused_layer2<<<ND2 / 128, 256, 0, stream>>>(h, pad2, cnt2, Wt2, b2, (float*)d_out);
}

// Round 11
// 414.226 us; speedup vs baseline: 1.0674x; 1.0608x over previous
//
#include <hip/hip_runtime.h>

static constexpr int FDIM = 128;
static constexpr int ND1  = 131072;
static constexpr int ND2  = 8192;
static constexpr int PADW = 64;   // padded adjacency slots/row; P(deg>=64)~1e-23 for Poisson(15)
static constexpr int LDP  = 56;   // ushort stride for A/W staging tiles

using bf16x8 = __attribute__((ext_vector_type(8))) short;
using u16x8  = __attribute__((ext_vector_type(8))) unsigned short;
using f32x4  = __attribute__((ext_vector_type(4))) float;

static __device__ __forceinline__ unsigned short f2bf(float f) {
  unsigned u = __float_as_uint(f);
  u = (u + 0x7FFFu + ((u >> 16) & 1u)) >> 16;   // round-to-nearest-even
  return (unsigned short)u;
}
static __device__ __forceinline__ float bf2f(unsigned short s) {
  return __uint_as_float(((unsigned)s) << 16);
}

// ---- build: graph-1 padded adjacency + weight prep (Wt1, Wt2) ---------------
__global__ void build1(const int* __restrict__ e1s, const int* __restrict__ e1d,
                       int* __restrict__ cnt1, int* __restrict__ pad1,
                       int E1, int nb_fill,
                       const float* __restrict__ Ws1, const float* __restrict__ Wn1,
                       unsigned short* __restrict__ Wt1,
                       const float* __restrict__ Ws2, const float* __restrict__ Wn2,
                       unsigned short* __restrict__ Wt2) {
  if ((int)blockIdx.x >= nb_fill) {   // ---- weight prep: 256 trailing blocks ----
    int t = (blockIdx.x - nb_fill) * 256 + threadIdx.x;   // 0..65535
    int which = t >> 15;
    int r = t & 32767;
    int col = r >> 8, k = r & 255;
    const float* Ws = which ? Ws2 : Ws1;
    const float* Wn = which ? Wn2 : Wn1;
    unsigned short* Wt = which ? Wt2 : Wt1;
    float v = (k < 128) ? Ws[k * 128 + col] : Wn[(k - 128) * 128 + col];
    Wt[col * 256 + k] = f2bf(v);
    return;
  }
  const int n1 = E1 >> 2;
  int t = blockIdx.x * 256 + threadIdx.x;
  if (t < n1) {
    int4 d = ((const int4*)e1d)[t];
    int4 s = ((const int4*)e1s)[t];
    int p;
    p = atomicAdd(&cnt1[d.x], 1); if (p < PADW) pad1[d.x * PADW + p] = s.x;
    p = atomicAdd(&cnt1[d.y], 1); if (p < PADW) pad1[d.y * PADW + p] = s.y;
    p = atomicAdd(&cnt1[d.z], 1); if (p < PADW) pad1[d.z * PADW + p] = s.z;
    p = atomicAdd(&cnt1[d.w], 1); if (p < PADW) pad1[d.w * PADW + p] = s.w;
  }
  if (blockIdx.x == 0) {               // generic tail (E1 % 4)
    int tt = threadIdx.x;
    if (tt < (E1 & 3)) {
      int e = E1 - 1 - tt, d = e1d[e];
      int p = atomicAdd(&cnt1[d], 1); if (p < PADW) pad1[d * PADW + p] = e1s[e];
    }
  }
}

// ---- gather-mean layer 1 (proven v3 shape) + graph-2 build in trailing blocks
__global__ __launch_bounds__(256)
void gather_mean1(const float* __restrict__ src, const int* __restrict__ pad,
                  const int* __restrict__ cnt, unsigned short* __restrict__ out,
                  int nrows, int nb_gather,
                  const int* __restrict__ e2s, const int* __restrict__ e2d,
                  int* __restrict__ cnt2, int* __restrict__ pad2, int E2) {
  if ((int)blockIdx.x >= nb_gather) {   // ---- graph-2 build, hidden under gather ----
    const int n2 = E2 >> 2;
    int t = (blockIdx.x - nb_gather) * 256 + threadIdx.x;
    if (t < n2) {
      int4 d = ((const int4*)e2d)[t];
      int4 s = ((const int4*)e2s)[t];
      int p;
      p = atomicAdd(&cnt2[d.x], 1); if (p < PADW) pad2[d.x * PADW + p] = s.x;
      p = atomicAdd(&cnt2[d.y], 1); if (p < PADW) pad2[d.y * PADW + p] = s.y;
      p = atomicAdd(&cnt2[d.z], 1); if (p < PADW) pad2[d.z * PADW + p] = s.z;
      p = atomicAdd(&cnt2[d.w], 1); if (p < PADW) pad2[d.w * PADW + p] = s.w;
    }
    if (blockIdx.x == (unsigned)nb_gather) {   // tail (E2 % 4)
      int tt = threadIdx.x;
      if (tt < (E2 & 3)) {
        int e = E2 - 1 - tt, d = e2d[e];
        int p = atomicAdd(&cnt2[d], 1); if (p < PADW) pad2[d * PADW + p] = e2s[e];
      }
    }
    return;
  }
  const int lane = threadIdx.x & 63;
  const int half = lane >> 5;
  const int sub  = lane & 31;
  const int wid  = (int)((blockIdx.x * 256u + threadIdx.x) >> 6);
  const int row  = wid * 2 + half;
  if (row >= nrows) return;
  const int degt = cnt[row];
  const int deg  = degt < PADW ? degt : PADW;   // index-safety clamp
  float ax = 0.f, ay = 0.f, az = 0.f, aw = 0.f;
  for (int base = 0; base < deg; base += 32) {
    int t = base + sub;
    int idx = pad[(size_t)row * PADW + (t < deg ? t : deg - 1)];   // coalesced, clamped
    const int lim = (deg - base) < 32 ? (deg - base) : 32;
    for (int b = 0; b < lim; b += 8) {
      float4 v[8];
      #pragma unroll
      for (int j = 0; j < 8; ++j) {
        int e = __shfl(idx, half * 32 + b + j);
        v[j] = *(const float4*)(src + (size_t)e * FDIM + sub * 4);
      }
      #pragma unroll
      for (int j = 0; j < 8; ++j) {
        float mk = (b + j) < lim ? 1.f : 0.f;
        ax = fmaf(v[j].x, mk, ax); ay = fmaf(v[j].y, mk, ay);
        az = fmaf(v[j].z, mk, az); aw = fmaf(v[j].w, mk, aw);
      }
    }
  }
  const float inv = 1.f / (float)(degt > 1 ? degt : 1);
  ushort4 o;
  o.x = f2bf(ax * inv); o.y = f2bf(ay * inv);
  o.z = f2bf(az * inv); o.w = f2bf(aw * inv);
  *(ushort4*)(out + (size_t)row * FDIM + sub * 4) = o;
}

// ---- gather-mean layer 2 over bf16 rows (h), 1024 blocks, full-GPU spread ---
__global__ __launch_bounds__(256)
void gather_mean2(const unsigned short* __restrict__ src, const int* __restrict__ pad,
                  const int* __restrict__ cnt, unsigned short* __restrict__ out, int nrows) {
  const int lane = threadIdx.x & 63;
  const int half = lane >> 5;
  const int sub  = lane & 31;
  const int wid  = (int)((blockIdx.x * 256u + threadIdx.x) >> 6);
  const int row  = wid * 2 + half;
  if (row >= nrows) return;
  const int degt = cnt[row];
  const int deg  = degt < PADW ? degt : PADW;
  float ax = 0.f, ay = 0.f, az = 0.f, aw = 0.f;
  for (int base = 0; base < deg; base += 32) {
    int t = base + sub;
    int idx = pad[(size_t)row * PADW + (t < deg ? t : deg - 1)];
    const int lim = (deg - base) < 32 ? (deg - base) : 32;
    for (int b = 0; b < lim; b += 8) {
      ushort4 v[8];
      #pragma unroll
      for (int j = 0; j < 8; ++j) {
        int e = __shfl(idx, half * 32 + b + j);
        v[j] = *(const ushort4*)(src + (size_t)e * FDIM + sub * 4);
      }
      #pragma unroll
      for (int j = 0; j < 8; ++j) {
        float mk = (b + j) < lim ? 1.f : 0.f;
        ax = fmaf(bf2f(v[j].x), mk, ax); ay = fmaf(bf2f(v[j].y), mk, ay);
        az = fmaf(bf2f(v[j].z), mk, az); aw = fmaf(bf2f(v[j].w), mk, aw);
      }
    }
  }
  const float inv = 1.f / (float)(degt > 1 ? degt : 1);
  ushort4 o;
  o.x = f2bf(ax * inv); o.y = f2bf(ay * inv);
  o.z = f2bf(az * inv); o.w = f2bf(aw * inv);
  *(ushort4*)(out + (size_t)row * FDIM + sub * 4) = o;
}

// ---- MFMA GEMM: Out = act([Ax|Am] @ [Wself;Wneigh] + b) ---------------------
template<bool RELU, bool AX_BF16, bool OUT_F32>
__global__ __launch_bounds__(256)
void gemm_mfma(const void* __restrict__ Axp,
               const unsigned short* __restrict__ Am,
               const unsigned short* __restrict__ Wt,
               const float* __restrict__ bias,
               void* __restrict__ Outp) {
  __shared__ unsigned short Asb[128 * LDP];
  __shared__ unsigned short Wsb[128 * LDP];
  const int tid  = threadIdx.x;
  const int lane = tid & 63;
  const int w    = tid >> 6;
  const int row0 = blockIdx.x * 128;
  const int p    = lane & 15;
  const int q    = lane >> 4;

  f32x4 acc[2][8];
  #pragma unroll
  for (int m = 0; m < 2; ++m)
    #pragma unroll
    for (int n = 0; n < 8; ++n) acc[m][n] = (f32x4){0.f, 0.f, 0.f, 0.f};

  const int sr = tid >> 1;            // staging row/col 0..127
  const int sk = (tid & 1) * 16;      // staging k-half

  for (int c = 0; c < 8; ++c) {
    const int kc = c * 32;
    const int kl = kc & 127;
    {
      const unsigned short* wsrc = Wt + (size_t)sr * 256 + kc + sk;
      u16x8 a = *(const u16x8*)(wsrc);
      u16x8 b = *(const u16x8*)(wsrc + 8);
      *(u16x8*)&Wsb[sr * LDP + sk]     = a;
      *(u16x8*)&Wsb[sr * LDP + sk + 8] = b;
    }
    if (AX_BF16 || c >= 4) {
      const unsigned short* asrc =
          (c < 4 ? (const unsigned short*)Axp : Am) + (size_t)(row0 + sr) * FDIM + kl + sk;
      u16x8 a = *(const u16x8*)(asrc);
      u16x8 b = *(const u16x8*)(asrc + 8);
      *(u16x8*)&Asb[sr * LDP + sk]     = a;
      *(u16x8*)&Asb[sr * LDP + sk + 8] = b;
    } else {
      const float* asrc = (const float*)Axp + (size_t)(row0 + sr) * FDIM + kl + sk;
      float4 f0 = *(const float4*)(asrc);
      float4 f1 = *(const float4*)(asrc + 4);
      float4 f2 = *(const float4*)(asrc + 8);
      float4 f3 = *(const float4*)(asrc + 12);
      u16x8 a, b;
      a[0] = f2bf(f0.x); a[1] = f2bf(f0.y); a[2] = f2bf(f0.z); a[3] = f2bf(f0.w);
      a[4] = f2bf(f1.x); a[5] = f2bf(f1.y); a[6] = f2bf(f1.z); a[7] = f2bf(f1.w);
      b[0] = f2bf(f2.x); b[1] = f2bf(f2.y); b[2] = f2bf(f2.z); b[3] = f2bf(f2.w);
      b[4] = f2bf(f3.x); b[5] = f2bf(f3.y); b[6] = f2bf(f3.z); b[7] = f2bf(f3.w);
      *(u16x8*)&Asb[sr * LDP + sk]     = a;
      *(u16x8*)&Asb[sr * LDP + sk + 8] = b;
    }
    __syncthreads();
    bf16x8 af[2];
    #pragma unroll
    for (int m = 0; m < 2; ++m)
      af[m] = *(const bf16x8*)&Asb[(w * 32 + m * 16 + p) * LDP + q * 8];
    #pragma unroll
    for (int n = 0; n < 8; ++n) {
      bf16x8 bfr = *(const bf16x8*)&Wsb[(n * 16 + p) * LDP + q * 8];
      acc[0][n] = __builtin_amdgcn_mfma_f32_16x16x32_bf16(af[0], bfr, acc[0][n], 0, 0, 0);
      acc[1][n] = __builtin_amdgcn_mfma_f32_16x16x32_bf16(af[1], bfr, acc[1][n], 0, 0, 0);
    }
    __syncthreads();
  }

  #pragma unroll
  for (int n = 0; n < 8; ++n) {
    const int col = n * 16 + p;
    const float bv = bias[col];
    #pragma unroll
    for (int m = 0; m < 2; ++m) {
      #pragma unroll
      for (int r = 0; r < 4; ++r) {
        float y = acc[m][n][r] + bv;
        if (RELU) y = fmaxf(y, 0.f);
        const size_t grow = (size_t)(row0 + w * 32 + m * 16 + q * 4 + r);
        if (OUT_F32) ((float*)Outp)[grow * FDIM + col] = y;
        else         ((unsigned short*)Outp)[grow * FDIM + col] = f2bf(y);
      }
    }
  }
}

extern "C" void kernel_launch(void* const* d_in, const int* in_sizes, int n_in,
                              void* d_out, int out_size, void* d_ws, size_t ws_size,
                              hipStream_t stream) {
  const float* x   = (const float*)d_in[0];
  const int*   e1s = (const int*)d_in[1];
  const int*   e1d = (const int*)d_in[2];
  const int*   e2s = (const int*)d_in[3];
  const int*   e2d = (const int*)d_in[4];
  const float* Ws1 = (const float*)d_in[7];
  const float* Wn1 = (const float*)d_in[8];
  const float* b1  = (const float*)d_in[9];
  const float* Ws2 = (const float*)d_in[10];
  const float* Wn2 = (const float*)d_in[11];
  const float* b2  = (const float*)d_in[12];
  const int E1 = in_sizes[1];
  const int E2 = in_sizes[3];

  char* pw = (char*)d_ws;
  unsigned short* agg1 = (unsigned short*)pw; pw += (size_t)ND1 * FDIM * 2;   // 32 MB
  unsigned short* h    = (unsigned short*)pw; pw += (size_t)ND1 * FDIM * 2;   // 32 MB
  unsigned short* agg2 = (unsigned short*)pw; pw += (size_t)ND2 * FDIM * 2;   //  2 MB
  unsigned short* Wt1  = (unsigned short*)pw; pw += (size_t)FDIM * 256 * 2;   // 64 KB
  unsigned short* Wt2  = (unsigned short*)pw; pw += (size_t)FDIM * 256 * 2;
  int* pad1 = (int*)pw; pw += (size_t)ND1 * PADW * 4;                          // 33.5 MB
  int* pad2 = (int*)pw; pw += (size_t)ND2 * PADW * 4;                          //  2 MB
  int* cnt1 = (int*)pw; pw += (size_t)ND1 * 4;                                 // 512 KB
  int* cnt2 = (int*)pw; pw += (size_t)ND2 * 4;                                 //  32 KB

  hipMemsetAsync(cnt1, 0, (size_t)(ND1 + ND2) * 4, stream);

  // graph-1 adjacency build + weight prep
  const int nb_fill1 = ((E1 >> 2) + 255) / 256;
  build1<<<nb_fill1 + 256, 256, 0, stream>>>(e1s, e1d, cnt1, pad1, E1, nb_fill1,
                                             Ws1, Wn1, Wt1, Ws2, Wn2, Wt2);

  // layer-1 gather (BW-bound) with graph-2 build hidden in trailing blocks
  const int nb_gather = ND1 / 8;
  const int nb_fill2  = ((E2 >> 2) + 255) / 256;
  gather_mean1<<<nb_gather + nb_fill2, 256, 0, stream>>>(x, pad1, cnt1, agg1, ND1,
                                                         nb_gather, e2s, e2d,
                                                         cnt2, pad2, E2);

  // layer-1 GEMM+ReLU -> h (bf16)
  gemm_mfma<true, false, false><<<ND1 / 128, 256, 0, stream>>>(x, agg1, Wt1, b1, h);

  // layer-2 gather (full-GPU spread) then GEMM -> out (f32)
  gather_mean2<<<ND2 / 8, 256, 0, stream>>>(h, pad2, cnt2, agg2, ND2);
  gemm_mfma<false, true, true><<<ND2 / 128, 256, 0, stream>>>(h, agg2, Wt2, b2, (float*)d_out);
}